// Round 4
// baseline (4227.535 us; speedup 1.0000x reference)
//
#include <hip/hip_runtime.h>

typedef unsigned short u16;
typedef __bf16 bf16x8 __attribute__((ext_vector_type(8)));
typedef float f32x4 __attribute__((ext_vector_type(4)));

#define NWG 256

__device__ __forceinline__ u16 f2bf(float f) {
  union { float f; unsigned u; } v; v.f = f;
  unsigned r = v.u + 0x7fffu + ((v.u >> 16) & 1u);
  return (u16)(r >> 16);
}
__device__ __forceinline__ float bf2f(u16 h) {
  union { unsigned u; float f; } v; v.u = ((unsigned)h) << 16;
  return v.f;
}
__device__ __forceinline__ float fsig(float x) { return 1.0f / (1.0f + __expf(-x)); }
__device__ __forceinline__ float ftanh(float x) {
  float a = fabsf(x);
  float e = __expf(2.0f * a);
  float t = 1.0f - 2.0f / (e + 1.0f);
  return copysignf(t, x);
}

// inputs [b][s][d] fp32 -> [s][b][d] bf16
__global__ __launch_bounds__(256) void k_cvt_in(const float* __restrict__ inp,
                                                u16* __restrict__ dst) {
  unsigned i = blockIdx.x * 256 + threadIdx.x;
  unsigned d8 = i & 63u;
  unsigned b = (i >> 6) & 63u;
  unsigned s = i >> 12;
  const float* src = inp + ((size_t)b * 512 + s) * 512 + (size_t)d8 * 8;
  float4 x0 = *(const float4*)src;
  float4 x1 = *(const float4*)(src + 4);
  union { u16 h[8]; uint4 v; } o;
  o.h[0] = f2bf(x0.x); o.h[1] = f2bf(x0.y); o.h[2] = f2bf(x0.z); o.h[3] = f2bf(x0.w);
  o.h[4] = f2bf(x1.x); o.h[5] = f2bf(x1.y); o.h[6] = f2bf(x1.z); o.h[7] = f2bf(x1.w);
  *(uint4*)(dst + ((size_t)s * 64 + b) * 512 + d8 * 8) = o.v;
}

// 4 gate matrices [K][1024] fp32 -> combined transposed [4096][K] bf16
__global__ __launch_bounds__(256) void k_cvt_w(const float* __restrict__ W0,
                                               const float* __restrict__ W1,
                                               const float* __restrict__ W2,
                                               const float* __restrict__ W3,
                                               int K, u16* __restrict__ dst) {
  unsigned i = blockIdx.x * 256 + threadIdx.x;
  unsigned kb = (unsigned)K >> 3;
  unsigned k8 = i % kb;
  unsigned n = i / kb;
  if (n >= 4096) return;
  unsigned gate = n >> 10, h = n & 1023u;
  const float* W = (gate == 0) ? W0 : (gate == 1) ? W1 : (gate == 2) ? W2 : W3;
  union { u16 hh[8]; uint4 v; } o;
#pragma unroll
  for (int q = 0; q < 8; ++q) o.hh[q] = f2bf(W[(size_t)(k8 * 8 + q) * 1024 + h]);
  *(uint4*)(dst + (size_t)n * K + k8 * 8) = o.v;
}

// zero the barrier region (flags[256] + gflags[16], 128B-strided) and init hbuf[0]
__global__ __launch_bounds__(256) void k_init(const float* __restrict__ H0,
                                              u16* __restrict__ hbuf,
                                              unsigned* __restrict__ bar) {
  unsigned i = blockIdx.x * 256 + threadIdx.x;
  if (i < 16384) bar[i] = 0u;
  if (i < 65536) hbuf[i] = f2bf(H0[i]);
}

// Xp GEMM: A [32768][512] bf16 (s,b-major), Bm [4096][512] bf16 (n-major) -> Xp [32768][4096] bf16
__global__ __launch_bounds__(256) void k_xp(const u16* __restrict__ A,
                                            const u16* __restrict__ Bm,
                                            u16* __restrict__ Xp) {
  __shared__ u16 Al[64][72];
  __shared__ u16 Bl[64][72];
  int t = threadIdx.x;
  int lane = t & 63, wid = t >> 6;
  int m0 = blockIdx.x * 64, n0 = blockIdx.y * 64;
  int quad = lane >> 4, l15 = lane & 15;
  f32x4 acc[4];
#pragma unroll
  for (int i = 0; i < 4; ++i) acc[i] = (f32x4){0.f, 0.f, 0.f, 0.f};
  int srow = t >> 2, sk = (t & 3) * 16;
  for (int kc = 0; kc < 512; kc += 64) {
    const u16* s1 = A + (size_t)(m0 + srow) * 512 + kc + sk;
    *(uint4*)&Al[srow][sk] = *(const uint4*)s1;
    *(uint4*)&Al[srow][sk + 8] = *(const uint4*)(s1 + 8);
    const u16* s2 = Bm + (size_t)(n0 + srow) * 512 + kc + sk;
    *(uint4*)&Bl[srow][sk] = *(const uint4*)s2;
    *(uint4*)&Bl[srow][sk + 8] = *(const uint4*)(s2 + 8);
    __syncthreads();
#pragma unroll
    for (int ks = 0; ks < 64; ks += 32) {
      bf16x8 a = *(const bf16x8*)&Al[wid * 16 + l15][ks + quad * 8];
#pragma unroll
      for (int nt = 0; nt < 4; ++nt) {
        bf16x8 b = *(const bf16x8*)&Bl[nt * 16 + l15][ks + quad * 8];
        acc[nt] = __builtin_amdgcn_mfma_f32_16x16x32_bf16(a, b, acc[nt], 0, 0, 0);
      }
    }
    __syncthreads();
  }
#pragma unroll
  for (int nt = 0; nt < 4; ++nt)
#pragma unroll
    for (int r = 0; r < 4; ++r) {
      size_t row = (size_t)m0 + wid * 16 + quad * 4 + r;  // C/D: row=quad*4+reg, col=lane&15
      Xp[row * 4096 + n0 + nt * 16 + l15] = f2bf(acc[nt][r]);
    }
}

// Persistent LSTM recurrence. 256 WGs x 512 threads. WG wg owns h = 4*wg .. 4*wg+3.
// Fence-free two-level barrier: sc1 stores write through to MALL; __syncthreads
// drains vmcnt before the arrival flag; hbuf is write-once-read-once so plain
// cached loads can never see stale data. 16 leader WGs aggregate 16 members each
// (1 poller per flag line), then 16 group flags are polled by t<16 of every WG
// (256 pollers/line, 4096 total) -- keeps poll traffic ~16x below R2's
// all-poll-all, which saturated the MALL.
__global__ __launch_bounds__(512) void k_recur(
    u16* hbuf, const u16* __restrict__ whc, const u16* __restrict__ wxc,
    const u16* xp, const u16* inpb, const float* __restrict__ C0,
    const float* __restrict__ bi, const float* __restrict__ bff,
    const float* __restrict__ bo, const float* __restrict__ bc,
    float* __restrict__ dout, unsigned* bar, int use_xp) {
  int t = threadIdx.x;
  int wg = blockIdx.x;
  int lane = t & 63;
  int wid = t >> 6;     // 0..7
  int kset = wid >> 2;  // 0..1 (K-split)
  int wm = wid & 3;     // m-tile (16 b-rows each)
  int h0 = wg << 2;
  int quad = lane >> 4;
  int ncol = lane & 15;

  unsigned* flags = bar;          // flags[wg] at bar[wg*32]
  unsigned* gflags = bar + 8192;  // gflags[g] at bar[8192 + g*32]

  __shared__ u16 whl[16][1032];  // Wh slice, [n][k], pad 8 -> 2-way-max bank aliasing
  __shared__ u16 wxl[16][520];   // Wx slice (path B)
  __shared__ float gt[2][4][16][17];
  __shared__ float biasl[16];

  {
    int n = t >> 5;
    int part = t & 31;
    int gate = n >> 2, j = n & 3;
    size_t colg = (size_t)gate * 1024 + h0 + j;
    const u16* src = whc + colg * 1024 + part * 32;
#pragma unroll
    for (int q = 0; q < 4; ++q)
      *(uint4*)&whl[n][part * 32 + q * 8] = *(const uint4*)(src + q * 8);
    if (!use_xp) {
      const u16* src2 = wxc + colg * 512 + part * 16;
#pragma unroll
      for (int q = 0; q < 2; ++q)
        *(uint4*)&wxl[n][part * 16 + q * 8] = *(const uint4*)(src2 + q * 8);
    }
  }
  if (t < 16) {
    int gate = t >> 2, j = t & 3;
    const float* bp = (gate == 0) ? bi : (gate == 1) ? bff : (gate == 2) ? bo : bc;
    biasl[t] = bp[h0 + j];
  }
  float Creg0 = 0.f, Creg1 = 0.f;
  if (t < 128) {
    int b = t >> 1, j2 = (t & 1) * 2;
    Creg0 = C0[b * 1024 + h0 + j2];
    Creg1 = C0[b * 1024 + h0 + j2 + 1];
  }

  int brow = wm * 16 + ncol;  // A-operand row (batch index) for this lane

  // xp column pointer for this lane (kset==0 lanes consume the x-projection)
  u16 xn0 = 0, xn1 = 0, xn2 = 0, xn3 = 0;
  const u16* xpc = 0;
  if (use_xp) {
    int gate = ncol >> 2, j = ncol & 3;
    xpc = xp + (size_t)(wm * 16 + quad * 4) * 4096 + gate * 1024 + h0 + j;
    if (kset == 0) {  // prefetch s=0
      xn0 = xpc[0]; xn1 = xpc[4096]; xn2 = xpc[8192]; xn3 = xpc[12288];
    }
  }
  __syncthreads();

  for (int s = 0; s < 512; ++s) {
    f32x4 acc = (f32x4){0.f, 0.f, 0.f, 0.f};
    f32x4 acc2 = (f32x4){0.f, 0.f, 0.f, 0.f};
    const u16* hrow = hbuf + (size_t)s * 65536 + (size_t)brow * 1024;
    if (use_xp) {
      if (kset == 0) {  // accumulator init from prefetched x-projection
        acc[0] = bf2f(xn0); acc[1] = bf2f(xn1);
        acc[2] = bf2f(xn2); acc[3] = bf2f(xn3);
      }
    } else {  // on-the-fly x-projection
      const u16* irow = inpb + (size_t)s * 32768 + (size_t)brow * 512;
#pragma unroll
      for (int kk = 0; kk < 8; ++kk) {
        int kb = kset * 256 + kk * 32 + quad * 8;
        bf16x8 a = *(const bf16x8*)(irow + kb);
        bf16x8 w = *(const bf16x8*)&wxl[ncol][kb];
        acc = __builtin_amdgcn_mfma_f32_16x16x32_bf16(a, w, acc, 0, 0, 0);
      }
    }
#pragma unroll
    for (int kk = 0; kk < 16; ++kk) {
      int kb = kset * 512 + kk * 32 + quad * 8;
      bf16x8 a = *(const bf16x8*)(hrow + kb);
      bf16x8 w = *(const bf16x8*)&whl[ncol][kb];
      if (kk & 1)
        acc2 = __builtin_amdgcn_mfma_f32_16x16x32_bf16(a, w, acc2, 0, 0, 0);
      else
        acc = __builtin_amdgcn_mfma_f32_16x16x32_bf16(a, w, acc, 0, 0, 0);
    }
    acc += acc2;
#pragma unroll
    for (int r = 0; r < 4; ++r)
      gt[kset][wm][quad * 4 + r][ncol] = acc[r];  // C/D: row=quad*4+r, col=lane&15
    __syncthreads();
    if (t < 128) {
      int b = t >> 1, j2 = (t & 1) * 2;
      int m = b & 15, w2 = b >> 4;
      float Hn[2], Cn[2];
#pragma unroll
      for (int e = 0; e < 2; ++e) {
        int j = j2 + e;
        float gi = gt[0][w2][m][j] + gt[1][w2][m][j] + biasl[j];
        float gf = gt[0][w2][m][4 + j] + gt[1][w2][m][4 + j] + biasl[4 + j];
        float go_ = gt[0][w2][m][8 + j] + gt[1][w2][m][8 + j] + biasl[8 + j];
        float gc = gt[0][w2][m][12 + j] + gt[1][w2][m][12 + j] + biasl[12 + j];
        float iv = fsig(gi), fv = fsig(gf), ov = fsig(go_), cv = ftanh(gc);
        float Cp = e ? Creg1 : Creg0;
        Cn[e] = fv * Cp + iv * cv;
        Hn[e] = ov * ftanh(Cn[e]);
      }
      Creg0 = Cn[0];
      Creg1 = Cn[1];
      // packed dword H store, sc1 write-through to MALL (cross-XCD visible)
      unsigned pack = (unsigned)f2bf(Hn[0]) | ((unsigned)f2bf(Hn[1]) << 16);
      unsigned* hp = (unsigned*)(hbuf + (size_t)(s + 1) * 65536 + b * 1024 + h0 + j2);
      __hip_atomic_store(hp, pack, __ATOMIC_RELAXED, __HIP_MEMORY_SCOPE_AGENT);
      if (s == 511) {
        dout[32768 + b * 1024 + h0 + j2] = Hn[0];      // Hf
        dout[32768 + b * 1024 + h0 + j2 + 1] = Hn[1];
        dout[98304 + b * 1024 + h0 + j2] = Cn[0];      // Cf
        dout[98304 + b * 1024 + h0 + j2 + 1] = Cn[1];
      }
    }
    // ---- fence-free two-level barrier ----
    unsigned s1 = (unsigned)(s + 1);
    __syncthreads();  // drains vmcnt: all H stores at the coherent point
    if (s1 < 512) {
      if (t == 0)
        __hip_atomic_store(&flags[wg * 32], s1, __ATOMIC_RELAXED,
                           __HIP_MEMORY_SCOPE_AGENT);
      // prefetch next step's xp while waiting (no dependency on the barrier)
      if (use_xp && kset == 0) {
        const u16* xpp = xpc + (size_t)s1 * 262144;
        xn0 = xpp[0]; xn1 = xpp[4096]; xn2 = xpp[8192]; xn3 = xpp[12288];
      }
      __asm__ volatile("" ::: "memory");  // keep prefetch above the spins
      if (wg < 16) {  // leader: aggregate my 16 members (1 poller per line)
        if (t < 16) {
          while (__hip_atomic_load(&flags[(wg * 16 + t) * 32], __ATOMIC_RELAXED,
                                   __HIP_MEMORY_SCOPE_AGENT) < s1)
            __builtin_amdgcn_s_sleep(1);
        }
        __syncthreads();
        if (t == 0)
          __hip_atomic_store(&gflags[wg * 32], s1, __ATOMIC_RELAXED,
                             __HIP_MEMORY_SCOPE_AGENT);
      }
      if (t < 16) {  // everyone: wait for the 16 group flags
        while (__hip_atomic_load(&gflags[t * 32], __ATOMIC_RELAXED,
                                 __HIP_MEMORY_SCOPE_AGENT) < s1)
          __builtin_amdgcn_s_sleep(1);
      }
      __syncthreads();
    }
  }
}

// pred[b][s] = H_t[b] . fc_W + fc_b   (one wave per row)
__global__ __launch_bounds__(256) void k_pred(const u16* __restrict__ hbuf,
                                              const float* __restrict__ fcW,
                                              const float* __restrict__ fcb,
                                              float* __restrict__ out) {
  __shared__ float w[1024];
  int t = threadIdx.x;
#pragma unroll
  for (int i = 0; i < 4; ++i) w[t + i * 256] = fcW[t + i * 256];
  __syncthreads();
  int wid = t >> 6, lane = t & 63;
  int row = blockIdx.x * 4 + wid;  // row = b*512 + s
  int b = row >> 9, s = row & 511;
  const u16* h = hbuf + (size_t)(s + 1) * 65536 + (size_t)b * 1024;
  float sum = 0.f;
#pragma unroll
  for (int it = 0; it < 16; ++it) {
    int hh = it * 64 + lane;
    sum += bf2f(h[hh]) * w[hh];
  }
#pragma unroll
  for (int o = 32; o > 0; o >>= 1) sum += __shfl_down(sum, o, 64);
  if (lane == 0) out[row] = sum + fcb[0];
}

extern "C" void kernel_launch(void* const* d_in, const int* in_sizes, int n_in,
                              void* d_out, int out_size, void* d_ws, size_t ws_size,
                              hipStream_t stream) {
  const float* inputs = (const float*)d_in[0];
  const float* H0 = (const float*)d_in[1];
  const float* C0 = (const float*)d_in[2];
  const float* Wxi = (const float*)d_in[3];
  const float* Whi = (const float*)d_in[4];
  const float* bi = (const float*)d_in[5];
  const float* Wxf = (const float*)d_in[6];
  const float* Whf = (const float*)d_in[7];
  const float* bff = (const float*)d_in[8];
  const float* Wxo = (const float*)d_in[9];
  const float* Who = (const float*)d_in[10];
  const float* bo = (const float*)d_in[11];
  const float* Wxc = (const float*)d_in[12];
  const float* Whc = (const float*)d_in[13];
  const float* bc = (const float*)d_in[14];
  const float* fcW = (const float*)d_in[15];
  const float* fcb = (const float*)d_in[16];
  float* out = (float*)d_out;

  char* ws = (char*)d_ws;
  size_t off = 0;
  auto take = [&](size_t bytes) {
    char* p = ws + off;
    off += (bytes + 255) & ~(size_t)255;
    return p;
  };
  unsigned* bar = (unsigned*)take(16384 * 4);           // flags[256] + gflags[16]
  u16* inpb = (u16*)take((size_t)512 * 64 * 512 * 2);   // 32 MB
  u16* wxcT = (u16*)take((size_t)4096 * 512 * 2);       // 4 MB
  u16* whcT = (u16*)take((size_t)4096 * 1024 * 2);      // 8 MB
  u16* hbuf = (u16*)take((size_t)513 * 64 * 1024 * 2);  // 64 MB
  u16* xpb = (u16*)take((size_t)32768 * 4096 * 2);      // 256 MB (path A only)
  size_t needA = off;
  int useA = (ws_size >= needA) ? 1 : 0;

  k_cvt_in<<<8192, 256, 0, stream>>>(inputs, inpb);
  k_cvt_w<<<1024, 256, 0, stream>>>(Wxi, Wxf, Wxo, Wxc, 512, wxcT);
  k_cvt_w<<<2048, 256, 0, stream>>>(Whi, Whf, Who, Whc, 1024, whcT);
  k_init<<<256, 256, 0, stream>>>(H0, hbuf, bar);
  if (useA) k_xp<<<dim3(512, 64), 256, 0, stream>>>(inpb, wxcT, xpb);
  k_recur<<<NWG, 512, 0, stream>>>(hbuf, whcT, wxcT, xpb, inpb, C0, bi, bff, bo,
                                   bc, out, bar, useA);
  k_pred<<<8192, 256, 0, stream>>>(hbuf, fcW, fcb, out);
}

// Round 5
// 4062.113 us; speedup vs baseline: 1.0407x; 1.0407x over previous
//
#include <hip/hip_runtime.h>

typedef unsigned short u16;
typedef __bf16 bf16x8 __attribute__((ext_vector_type(8)));
typedef float f32x4 __attribute__((ext_vector_type(4)));

#define NWG 256

__device__ __forceinline__ u16 f2bf(float f) {
  union { float f; unsigned u; } v; v.f = f;
  unsigned r = v.u + 0x7fffu + ((v.u >> 16) & 1u);
  return (u16)(r >> 16);
}
__device__ __forceinline__ float bf2f(u16 h) {
  union { unsigned u; float f; } v; v.u = ((unsigned)h) << 16;
  return v.f;
}
__device__ __forceinline__ float fsig(float x) { return 1.0f / (1.0f + __expf(-x)); }
__device__ __forceinline__ float ftanh(float x) {
  float a = fabsf(x);
  float e = __expf(2.0f * a);
  float t = 1.0f - 2.0f / (e + 1.0f);
  return copysignf(t, x);
}

// inputs [b][s][d] fp32 -> [s][b][d] bf16
__global__ __launch_bounds__(256) void k_cvt_in(const float* __restrict__ inp,
                                                u16* __restrict__ dst) {
  unsigned i = blockIdx.x * 256 + threadIdx.x;
  unsigned d8 = i & 63u;
  unsigned b = (i >> 6) & 63u;
  unsigned s = i >> 12;
  const float* src = inp + ((size_t)b * 512 + s) * 512 + (size_t)d8 * 8;
  float4 x0 = *(const float4*)src;
  float4 x1 = *(const float4*)(src + 4);
  union { u16 h[8]; uint4 v; } o;
  o.h[0] = f2bf(x0.x); o.h[1] = f2bf(x0.y); o.h[2] = f2bf(x0.z); o.h[3] = f2bf(x0.w);
  o.h[4] = f2bf(x1.x); o.h[5] = f2bf(x1.y); o.h[6] = f2bf(x1.z); o.h[7] = f2bf(x1.w);
  *(uint4*)(dst + ((size_t)s * 64 + b) * 512 + d8 * 8) = o.v;
}

// 4 gate matrices [K][1024] fp32 -> combined transposed [4096][K] bf16
__global__ __launch_bounds__(256) void k_cvt_w(const float* __restrict__ W0,
                                               const float* __restrict__ W1,
                                               const float* __restrict__ W2,
                                               const float* __restrict__ W3,
                                               int K, u16* __restrict__ dst) {
  unsigned i = blockIdx.x * 256 + threadIdx.x;
  unsigned kb = (unsigned)K >> 3;
  unsigned k8 = i % kb;
  unsigned n = i / kb;
  if (n >= 4096) return;
  unsigned gate = n >> 10, h = n & 1023u;
  const float* W = (gate == 0) ? W0 : (gate == 1) ? W1 : (gate == 2) ? W2 : W3;
  union { u16 hh[8]; uint4 v; } o;
#pragma unroll
  for (int q = 0; q < 8; ++q) o.hh[q] = f2bf(W[(size_t)(k8 * 8 + q) * 1024 + h]);
  *(uint4*)(dst + (size_t)n * K + k8 * 8) = o.v;
}

// zero the barrier region and init hbuf[0]
__global__ __launch_bounds__(256) void k_init(const float* __restrict__ H0,
                                              u16* __restrict__ hbuf,
                                              unsigned* __restrict__ bar) {
  unsigned i = blockIdx.x * 256 + threadIdx.x;
  if (i < 16384) bar[i] = 0u;
  if (i < 65536) hbuf[i] = f2bf(H0[i]);
}

// Xp GEMM: A [32768][512] bf16 (s,b-major), Bm [4096][512] bf16 (n-major) -> Xp [32768][4096] bf16
__global__ __launch_bounds__(256) void k_xp(const u16* __restrict__ A,
                                            const u16* __restrict__ Bm,
                                            u16* __restrict__ Xp) {
  __shared__ u16 Al[64][72];
  __shared__ u16 Bl[64][72];
  int t = threadIdx.x;
  int lane = t & 63, wid = t >> 6;
  int m0 = blockIdx.x * 64, n0 = blockIdx.y * 64;
  int quad = lane >> 4, l15 = lane & 15;
  f32x4 acc[4];
#pragma unroll
  for (int i = 0; i < 4; ++i) acc[i] = (f32x4){0.f, 0.f, 0.f, 0.f};
  int srow = t >> 2, sk = (t & 3) * 16;
  for (int kc = 0; kc < 512; kc += 64) {
    const u16* s1 = A + (size_t)(m0 + srow) * 512 + kc + sk;
    *(uint4*)&Al[srow][sk] = *(const uint4*)s1;
    *(uint4*)&Al[srow][sk + 8] = *(const uint4*)(s1 + 8);
    const u16* s2 = Bm + (size_t)(n0 + srow) * 512 + kc + sk;
    *(uint4*)&Bl[srow][sk] = *(const uint4*)s2;
    *(uint4*)&Bl[srow][sk + 8] = *(const uint4*)(s2 + 8);
    __syncthreads();
#pragma unroll
    for (int ks = 0; ks < 64; ks += 32) {
      bf16x8 a = *(const bf16x8*)&Al[wid * 16 + l15][ks + quad * 8];
#pragma unroll
      for (int nt = 0; nt < 4; ++nt) {
        bf16x8 b = *(const bf16x8*)&Bl[nt * 16 + l15][ks + quad * 8];
        acc[nt] = __builtin_amdgcn_mfma_f32_16x16x32_bf16(a, b, acc[nt], 0, 0, 0);
      }
    }
    __syncthreads();
  }
#pragma unroll
  for (int nt = 0; nt < 4; ++nt)
#pragma unroll
    for (int r = 0; r < 4; ++r) {
      size_t row = (size_t)m0 + wid * 16 + quad * 4 + r;  // C/D: row=quad*4+reg, col=lane&15
      Xp[row * 4096 + n0 + nt * 16 + l15] = f2bf(acc[nt][r]);
    }
}

// Persistent LSTM recurrence. 256 WGs x 512 threads. WG wg owns h = 4*wg .. 4*wg+3.
// Wh fragments live in REGISTERS (16 x bf16x8 = 64 VGPRs/lane, loop-invariant):
// the K-loop is global_load_dwordx4(H) + MFMA only -- no LDS reads, no bank
// conflicts (R3 had 1.18e8 conflict-cycles from the whl tile's 4*ncol%32 bank map).
// Fence-free all-poll-all barrier (R2-validated): sc1 stores write through to the
// coherent point; __syncthreads drains vmcnt before the arrival flag; hbuf is
// write-once-read-once so plain cached loads can never be stale.
__global__ __launch_bounds__(512, 2) void k_recur(
    u16* hbuf, const u16* __restrict__ whc, const u16* __restrict__ wxc,
    const u16* xp, const u16* inpb, const float* __restrict__ C0,
    const float* __restrict__ bi, const float* __restrict__ bff,
    const float* __restrict__ bo, const float* __restrict__ bc,
    float* __restrict__ dout, unsigned* bar, int use_xp) {
  int t = threadIdx.x;
  int wg = blockIdx.x;
  int lane = t & 63;
  int wid = t >> 6;     // 0..7
  int kset = wid >> 2;  // 0..1 (K-split)
  int wm = wid & 3;     // m-tile (16 b-rows each)
  int h0 = wg << 2;
  int quad = lane >> 4;
  int ncol = lane & 15;

  unsigned* flags = bar;  // flags[wg] at bar[wg*32] (128B lines)

  __shared__ u16 wxl[16][520];  // Wx slice (path B only)
  __shared__ float gt[2][4][16][17];
  __shared__ float biasl[16];

  // ---- Wh fragments into registers (loop-invariant) ----
  int gate = ncol >> 2, j = ncol & 3;
  size_t colg = (size_t)gate * 1024 + h0 + j;
  bf16x8 wreg[16];
  {
    const u16* wb = whc + colg * 1024 + kset * 512 + quad * 8;
#pragma unroll
    for (int kk = 0; kk < 16; ++kk) wreg[kk] = *(const bf16x8*)(wb + kk * 32);
  }
  if (!use_xp) {
    int n = t >> 5;
    int part = t & 31;
    int g2 = n >> 2, j2n = n & 3;
    size_t cg = (size_t)g2 * 1024 + h0 + j2n;
    const u16* src2 = wxc + cg * 512 + part * 16;
#pragma unroll
    for (int q = 0; q < 2; ++q)
      *(uint4*)&wxl[n][part * 16 + q * 8] = *(const uint4*)(src2 + q * 8);
  }
  if (t < 16) {
    int g3 = t >> 2, j3 = t & 3;
    const float* bp = (g3 == 0) ? bi : (g3 == 1) ? bff : (g3 == 2) ? bo : bc;
    biasl[t] = bp[h0 + j3];
  }
  float Creg0 = 0.f, Creg1 = 0.f;
  if (t < 128) {
    int b = t >> 1, j2 = (t & 1) * 2;
    Creg0 = C0[b * 1024 + h0 + j2];
    Creg1 = C0[b * 1024 + h0 + j2 + 1];
  }

  int brow = wm * 16 + ncol;  // A-operand row (batch index) for this lane

  // xp column pointer for this lane (kset==0 lanes consume the x-projection)
  u16 xn0 = 0, xn1 = 0, xn2 = 0, xn3 = 0;
  const u16* xpc = 0;
  if (use_xp) {
    xpc = xp + (size_t)(wm * 16 + quad * 4) * 4096 + gate * 1024 + h0 + j;
    if (kset == 0) {  // prefetch s=0
      xn0 = xpc[0]; xn1 = xpc[4096]; xn2 = xpc[8192]; xn3 = xpc[12288];
    }
  }
  __syncthreads();

  for (int s = 0; s < 512; ++s) {
    f32x4 acc = (f32x4){0.f, 0.f, 0.f, 0.f};
    f32x4 acc2 = (f32x4){0.f, 0.f, 0.f, 0.f};
    const u16* hrow = hbuf + (size_t)s * 65536 + (size_t)brow * 1024 + kset * 512;
    if (use_xp) {
      if (kset == 0) {  // accumulator init from prefetched x-projection
        acc[0] = bf2f(xn0); acc[1] = bf2f(xn1);
        acc[2] = bf2f(xn2); acc[3] = bf2f(xn3);
      }
    } else {  // on-the-fly x-projection
      const u16* irow = inpb + (size_t)s * 32768 + (size_t)brow * 512;
#pragma unroll
      for (int kk = 0; kk < 8; ++kk) {
        int kb = kset * 256 + kk * 32 + quad * 8;
        bf16x8 a = *(const bf16x8*)(irow + kb);
        bf16x8 w = *(const bf16x8*)&wxl[ncol][kb];
        acc = __builtin_amdgcn_mfma_f32_16x16x32_bf16(a, w, acc, 0, 0, 0);
      }
    }
#pragma unroll
    for (int kk = 0; kk < 16; ++kk) {
      bf16x8 a = *(const bf16x8*)(hrow + kk * 32 + quad * 8);
      if (kk & 1)
        acc2 = __builtin_amdgcn_mfma_f32_16x16x32_bf16(a, wreg[kk], acc2, 0, 0, 0);
      else
        acc = __builtin_amdgcn_mfma_f32_16x16x32_bf16(a, wreg[kk], acc, 0, 0, 0);
    }
    acc += acc2;
#pragma unroll
    for (int r = 0; r < 4; ++r)
      gt[kset][wm][quad * 4 + r][ncol] = acc[r];  // C/D: row=quad*4+r, col=lane&15
    __syncthreads();
    if (t < 128) {
      int b = t >> 1, j2 = (t & 1) * 2;
      int m = b & 15, w2 = b >> 4;
      float Hn[2], Cn[2];
#pragma unroll
      for (int e = 0; e < 2; ++e) {
        int jj = j2 + e;
        float gi = gt[0][w2][m][jj] + gt[1][w2][m][jj] + biasl[jj];
        float gf = gt[0][w2][m][4 + jj] + gt[1][w2][m][4 + jj] + biasl[4 + jj];
        float go_ = gt[0][w2][m][8 + jj] + gt[1][w2][m][8 + jj] + biasl[8 + jj];
        float gc = gt[0][w2][m][12 + jj] + gt[1][w2][m][12 + jj] + biasl[12 + jj];
        float iv = fsig(gi), fv = fsig(gf), ov = fsig(go_), cv = ftanh(gc);
        float Cp = e ? Creg1 : Creg0;
        Cn[e] = fv * Cp + iv * cv;
        Hn[e] = ov * ftanh(Cn[e]);
      }
      Creg0 = Cn[0];
      Creg1 = Cn[1];
      // packed dword H store, sc1 write-through to the coherent point
      unsigned pack = (unsigned)f2bf(Hn[0]) | ((unsigned)f2bf(Hn[1]) << 16);
      unsigned* hp = (unsigned*)(hbuf + (size_t)(s + 1) * 65536 + b * 1024 + h0 + j2);
      __hip_atomic_store(hp, pack, __ATOMIC_RELAXED, __HIP_MEMORY_SCOPE_AGENT);
      if (s == 511) {
        dout[32768 + b * 1024 + h0 + j2] = Hn[0];      // Hf
        dout[32768 + b * 1024 + h0 + j2 + 1] = Hn[1];
        dout[98304 + b * 1024 + h0 + j2] = Cn[0];      // Cf
        dout[98304 + b * 1024 + h0 + j2 + 1] = Cn[1];
      }
    }
    // ---- fence-free all-poll-all barrier ----
    unsigned s1 = (unsigned)(s + 1);
    __syncthreads();  // drains vmcnt: all H stores at the coherent point
    if (s1 < 512) {
      if (t == 0)
        __hip_atomic_store(&flags[wg * 32], s1, __ATOMIC_RELAXED,
                           __HIP_MEMORY_SCOPE_AGENT);
      // prefetch next step's xp while waiting (no dependency on the barrier)
      if (use_xp && kset == 0) {
        const u16* xpp = xpc + (size_t)s1 * 262144;
        xn0 = xpp[0]; xn1 = xpp[4096]; xn2 = xpp[8192]; xn3 = xpp[12288];
      }
      __asm__ volatile("" ::: "memory");  // keep prefetch above the spin
      if (t < 256) {  // all-poll-all: thread t waits for WG t's arrival
        while (__hip_atomic_load(&flags[t * 32], __ATOMIC_RELAXED,
                                 __HIP_MEMORY_SCOPE_AGENT) < s1)
          __builtin_amdgcn_s_sleep(2);
      }
      __syncthreads();
    }
  }
}

// pred[b][s] = H_t[b] . fc_W + fc_b   (one wave per row)
__global__ __launch_bounds__(256) void k_pred(const u16* __restrict__ hbuf,
                                              const float* __restrict__ fcW,
                                              const float* __restrict__ fcb,
                                              float* __restrict__ out) {
  __shared__ float w[1024];
  int t = threadIdx.x;
#pragma unroll
  for (int i = 0; i < 4; ++i) w[t + i * 256] = fcW[t + i * 256];
  __syncthreads();
  int wid = t >> 6, lane = t & 63;
  int row = blockIdx.x * 4 + wid;  // row = b*512 + s
  int b = row >> 9, s = row & 511;
  const u16* h = hbuf + (size_t)(s + 1) * 65536 + (size_t)b * 1024;
  float sum = 0.f;
#pragma unroll
  for (int it = 0; it < 16; ++it) {
    int hh = it * 64 + lane;
    sum += bf2f(h[hh]) * w[hh];
  }
#pragma unroll
  for (int o = 32; o > 0; o >>= 1) sum += __shfl_down(sum, o, 64);
  if (lane == 0) out[row] = sum + fcb[0];
}

extern "C" void kernel_launch(void* const* d_in, const int* in_sizes, int n_in,
                              void* d_out, int out_size, void* d_ws, size_t ws_size,
                              hipStream_t stream) {
  const float* inputs = (const float*)d_in[0];
  const float* H0 = (const float*)d_in[1];
  const float* C0 = (const float*)d_in[2];
  const float* Wxi = (const float*)d_in[3];
  const float* Whi = (const float*)d_in[4];
  const float* bi = (const float*)d_in[5];
  const float* Wxf = (const float*)d_in[6];
  const float* Whf = (const float*)d_in[7];
  const float* bff = (const float*)d_in[8];
  const float* Wxo = (const float*)d_in[9];
  const float* Who = (const float*)d_in[10];
  const float* bo = (const float*)d_in[11];
  const float* Wxc = (const float*)d_in[12];
  const float* Whc = (const float*)d_in[13];
  const float* bc = (const float*)d_in[14];
  const float* fcW = (const float*)d_in[15];
  const float* fcb = (const float*)d_in[16];
  float* out = (float*)d_out;

  char* ws = (char*)d_ws;
  size_t off = 0;
  auto take = [&](size_t bytes) {
    char* p = ws + off;
    off += (bytes + 255) & ~(size_t)255;
    return p;
  };
  unsigned* bar = (unsigned*)take(16384 * 4);           // flags[256] (128B-strided)
  u16* inpb = (u16*)take((size_t)512 * 64 * 512 * 2);   // 32 MB
  u16* wxcT = (u16*)take((size_t)4096 * 512 * 2);       // 4 MB
  u16* whcT = (u16*)take((size_t)4096 * 1024 * 2);      // 8 MB
  u16* hbuf = (u16*)take((size_t)513 * 64 * 1024 * 2);  // 64 MB
  u16* xpb = (u16*)take((size_t)32768 * 4096 * 2);      // 256 MB (path A only)
  size_t needA = off;
  int useA = (ws_size >= needA) ? 1 : 0;

  k_cvt_in<<<8192, 256, 0, stream>>>(inputs, inpb);
  k_cvt_w<<<1024, 256, 0, stream>>>(Wxi, Wxf, Wxo, Wxc, 512, wxcT);
  k_cvt_w<<<2048, 256, 0, stream>>>(Whi, Whf, Who, Whc, 1024, whcT);
  k_init<<<256, 256, 0, stream>>>(H0, hbuf, bar);
  if (useA) k_xp<<<dim3(512, 64), 256, 0, stream>>>(inpb, wxcT, xpb);
  k_recur<<<NWG, 512, 0, stream>>>(hbuf, whcT, wxcT, xpb, inpb, C0, bi, bff, bo,
                                   bc, out, bar, useA);
  k_pred<<<8192, 256, 0, stream>>>(hbuf, fcW, fcb, out);
}